// Round 4
// baseline (1953.464 us; speedup 1.0000x reference)
//
#include <hip/hip_runtime.h>

#define SS 1024
#define FF 64
#define HH 64
#define NG 256    // 4H gate columns

__device__ __forceinline__ float sigmoidf_(float x) {
    return __builtin_amdgcn_rcpf(1.0f + __expf(-x));
}
__device__ __forceinline__ float tanhf_(float x) {
    return 1.0f - 2.0f * __builtin_amdgcn_rcpf(__expf(2.0f * x) + 1.0f);
}

#define REP32(M) \
  M(0) M(1) M(2) M(3) M(4) M(5) M(6) M(7) \
  M(8) M(9) M(10) M(11) M(12) M(13) M(14) M(15) \
  M(16) M(17) M(18) M(19) M(20) M(21) M(22) M(23) \
  M(24) M(25) M(26) M(27) M(28) M(29) M(30) M(31)
#define REP64(M) REP32(M) \
  M(32) M(33) M(34) M(35) M(36) M(37) M(38) M(39) \
  M(40) M(41) M(42) M(43) M(44) M(45) M(46) M(47) \
  M(48) M(49) M(50) M(51) M(52) M(53) M(54) M(55) \
  M(56) M(57) M(58) M(59) M(60) M(61) M(62) M(63)

// ================= Kernel 1: xz = x @ Wx + bias =================
// Grid: (256*CS)/128 blocks, 256 threads. Block handles 128 consecutive rows
// (one b, CS multiple of 128). Thread g owns gate column g; weights in VGPRs.
// x rows staged coalesced into LDS (double-buffered), read back as same-address
// broadcasts (conflict-free).
#define DECL_W1(i)  float wx##i;
#define LOAD_W1(i)  wx##i = wk[(i) * NG + g];
#define PIN_W1(i)   asm volatile("" : "+v"(wx##i));

#define K1F(I, A, B_, C_, D_) { const float4 v = xr4[I]; \
    a0 = __builtin_fmaf(v.x, wx##A,  a0); a1 = __builtin_fmaf(v.y, wx##B_, a1); \
    a2 = __builtin_fmaf(v.z, wx##C_, a2); a3 = __builtin_fmaf(v.w, wx##D_, a3); }

__global__ __launch_bounds__(256, 4)
void xz_gemm(const float* __restrict__ x, const float* __restrict__ wk,
             const float* __restrict__ bias, float* __restrict__ xz,
             int t0, int cs_shift) {
    const int CS  = 1 << cs_shift;
    const int tid = threadIdx.x;
    const int g   = tid;
    const int row0 = blockIdx.x * 128;          // row within [0, 256*CS)
    const int b    = row0 >> cs_shift;
    const int tl0  = row0 & (CS - 1);

    const float4* __restrict__ s4 =
        (const float4*)(x + ((size_t)b * SS + t0 + tl0) * FF);
    float* __restrict__ xzo = xz + ((size_t)b * CS + tl0) * NG + g;

    REP64(DECL_W1)
    REP64(LOAD_W1)
    REP64(PIN_W1)
    const float bg = bias[g];

    __shared__ float4 xs[2][512];               // 2 x 8KB (32 rows x 64 f)

    // stage tile 0
    xs[0][tid]       = s4[tid];
    xs[0][tid + 256] = s4[tid + 256];
    __syncthreads();

    for (int tile = 0; tile < 4; ++tile) {
        const int buf = tile & 1;
        float4 v0, v1;
        if (tile < 3) {                          // loads in flight during compute
            v0 = s4[(tile + 1) * 512 + tid];
            v1 = s4[(tile + 1) * 512 + tid + 256];
        }
        for (int r = 0; r < 32; ++r) {
            const float4* __restrict__ xr4 = &xs[buf][r * 16];
            float a0 = bg, a1 = 0.0f, a2 = 0.0f, a3 = 0.0f;
            K1F(0,0,1,2,3)     K1F(1,4,5,6,7)     K1F(2,8,9,10,11)   K1F(3,12,13,14,15)
            K1F(4,16,17,18,19) K1F(5,20,21,22,23) K1F(6,24,25,26,27) K1F(7,28,29,30,31)
            K1F(8,32,33,34,35) K1F(9,36,37,38,39) K1F(10,40,41,42,43) K1F(11,44,45,46,47)
            K1F(12,48,49,50,51) K1F(13,52,53,54,55) K1F(14,56,57,58,59) K1F(15,60,61,62,63)
            xzo[(size_t)(tile * 32 + r) * NG] = (a0 + a1) + (a2 + a3);
        }
        if (tile < 3) {
            xs[buf ^ 1][tid]       = v0;
            xs[buf ^ 1][tid + 256] = v1;
        }
        __syncthreads();
    }
}

// ================= Kernel 2: recurrence over a CS-step chunk =================
#define DECL_WR(i)  float wh##i;
#define LOAD_WR(i)  wh##i = rk[(kofs + i) * NG + g];
#define PIN_WR(i)   asm volatile("" : "+v"(wh##i));

#define FHR4(i0,i1,i2,i3) \
  a0 += __int_as_float(__builtin_amdgcn_readlane(hb, kofs + i0)) * wh##i0; \
  a1 += __int_as_float(__builtin_amdgcn_readlane(hb, kofs + i1)) * wh##i1; \
  a2 += __int_as_float(__builtin_amdgcn_readlane(hb, kofs + i2)) * wh##i2; \
  a3 += __int_as_float(__builtin_amdgcn_readlane(hb, kofs + i3)) * wh##i3;
#define FHR_ALL FHR4(0,1,2,3) FHR4(4,5,6,7) FHR4(8,9,10,11) FHR4(12,13,14,15) \
                FHR4(16,17,18,19) FHR4(20,21,22,23) FHR4(24,25,26,27) FHR4(28,29,30,31)

// Raw barrier: only drain LDS (lgkmcnt) -- leaves xz prefetch (vmcnt) in
// flight across the barrier (the __syncthreads vmcnt(0) drain was round 3's
// ~900cy/step HBM-latency exposure).
#define RAW_BARRIER() asm volatile("s_waitcnt lgkmcnt(0)\n\ts_barrier" ::: "memory")

#define STEPR(T, P, TN, BSEL) do {                                             \
    const float xzv = P;                                                       \
    if (ld) { const int ti = ((TN) < CS) ? (TN) : (CS - 1);                    \
              P = xzb[(size_t)ti * NG + g]; }                                  \
    float a0 = ld ? xzv : 0.0f, a1 = 0.0f, a2 = 0.0f, a3 = 0.0f;               \
    const int hb = __float_as_int(h);                                          \
    FHR_ALL                                                                    \
    zbuf[BSEL][tid] = (a0 + a1) + (a2 + a3);                                   \
    RAW_BARRIER();                                                             \
    const float zi = zbuf[BSEL][lane]       + zbuf[BSEL][256 + lane];          \
    const float zf = zbuf[BSEL][64 + lane]  + zbuf[BSEL][320 + lane];          \
    const float zc = zbuf[BSEL][128 + lane] + zbuf[BSEL][384 + lane];          \
    const float zo = zbuf[BSEL][192 + lane] + zbuf[BSEL][448 + lane];          \
    const float ig = sigmoidf_(zi);                                            \
    const float fg = sigmoidf_(zf);                                            \
    const float og = sigmoidf_(zo);                                            \
    c = fg * c + ig * tanhf_(zc);                                              \
    h = og * tanhf_(c);                                                        \
    if ((tid >> 6) == 7) {                                                     \
        float r = h * dwl;                                                     \
        r += __shfl_xor(r, 32, 64); r += __shfl_xor(r, 16, 64);                \
        r += __shfl_xor(r, 8, 64);  r += __shfl_xor(r, 4, 64);                 \
        r += __shfl_xor(r, 2, 64);  r += __shfl_xor(r, 1, 64);                 \
        if (lane == 0) outb[T] = sigmoidf_(r + db0);                           \
    }                                                                          \
} while (0)

__global__ __launch_bounds__(512, 2)
void lstm_rec(const float* __restrict__ xz, const float* __restrict__ rk,
              const float* __restrict__ dw, const float* __restrict__ db,
              float* __restrict__ out, float* __restrict__ state,
              int t0, int cs_shift, int init) {
    const int CS   = 1 << cs_shift;
    const int b    = blockIdx.x;
    const int tid  = threadIdx.x;
    const int lane = tid & 63;
    const int g    = tid & 255;
    const int kofs = __builtin_amdgcn_readfirstlane((tid >> 8) * 32); // 0 or 32

    REP32(DECL_WR)
    REP32(LOAD_WR)
    REP32(PIN_WR)
    const float dwl = dw[lane];
    const float db0 = db[0];

    __shared__ float zbuf[2][512];

    float* __restrict__ sh = state;                 // [256][64]
    float* __restrict__ sc = state + 256 * 64;
    float h, c;
    if (init) { h = 0.0f; c = 0.0f; }
    else      { h = sh[b * 64 + lane]; c = sc[b * 64 + lane]; }

    const float* __restrict__ xzb  = xz + (size_t)b * CS * NG;
    float* __restrict__       outb = out + (size_t)b * SS;
    const bool ld = (kofs == 0);

    float pA = 0.0f, pB = 0.0f;
    if (ld) { pA = xzb[g]; pB = xzb[NG + g]; }      // rows 0,1 of chunk

    for (int tl = 0; tl < CS; tl += 2) {
        STEPR(t0 + tl,     pA, tl + 2, 0);
        STEPR(t0 + tl + 1, pB, tl + 3, 1);
    }

    if (tid < 64) { sh[b * 64 + tid] = h; sc[b * 64 + tid] = c; }
}

// ================= Fallback (round-3 fused kernel) — used only if ws too small
#define DECL_WF(i)  float fwx##i, fwh##i;
#define LOAD_WF(i)  fwx##i = wk[(kofs + i) * NG + g]; fwh##i = rk[(kofs + i) * NG + g];
#define PIN_WF(i)   asm volatile("" : "+v"(fwx##i), "+v"(fwh##i));
#define DECL_XF(i)  float fxA##i, fxB##i;
#define LOAD_XAF(i) fxA##i = xb[offA + i];
#define LOAD_XBF(i) fxB##i = xb[offB + i];
#define FHF4(i0,i1,i2,i3) \
  a0 += __int_as_float(__builtin_amdgcn_readlane(hb, kofs + i0)) * fwh##i0; \
  a1 += __int_as_float(__builtin_amdgcn_readlane(hb, kofs + i1)) * fwh##i1; \
  a2 += __int_as_float(__builtin_amdgcn_readlane(hb, kofs + i2)) * fwh##i2; \
  a3 += __int_as_float(__builtin_amdgcn_readlane(hb, kofs + i3)) * fwh##i3;
#define FXF4(L,i0,i1,i2,i3) \
  a0 += fx##L##i0 * fwx##i0; a1 += fx##L##i1 * fwx##i1; \
  a2 += fx##L##i2 * fwx##i2; a3 += fx##L##i3 * fwx##i3;
#define FHF_ALL FHF4(0,1,2,3) FHF4(4,5,6,7) FHF4(8,9,10,11) FHF4(12,13,14,15) \
                FHF4(16,17,18,19) FHF4(20,21,22,23) FHF4(24,25,26,27) FHF4(28,29,30,31)
#define FXF_ALL(L) FXF4(L,0,1,2,3) FXF4(L,4,5,6,7) FXF4(L,8,9,10,11) FXF4(L,12,13,14,15) \
                   FXF4(L,16,17,18,19) FXF4(L,20,21,22,23) FXF4(L,24,25,26,27) FXF4(L,28,29,30,31)
#define STEPF(t, L) do {                                                       \
    const int bsel = (t) & 1;                                                  \
    float a0 = bg, a1 = 0.0f, a2 = 0.0f, a3 = 0.0f;                            \
    const int hb = __float_as_int(h);                                          \
    FHF_ALL                                                                    \
    FXF_ALL(L)                                                                 \
    zbuf[bsel][tid] = (a0 + a1) + (a2 + a3);                                   \
    __syncthreads();                                                           \
    const float zi = zbuf[bsel][lane]       + zbuf[bsel][256 + lane];          \
    const float zf = zbuf[bsel][64 + lane]  + zbuf[bsel][320 + lane];          \
    const float zc = zbuf[bsel][128 + lane] + zbuf[bsel][384 + lane];          \
    const float zo = zbuf[bsel][192 + lane] + zbuf[bsel][448 + lane];          \
    const float ig = sigmoidf_(zi);                                            \
    const float fg = sigmoidf_(zf);                                            \
    const float og = sigmoidf_(zo);                                            \
    c = fg * c + ig * tanhf_(zc);                                              \
    h = og * tanhf_(c);                                                        \
    if ((tid >> 6) == 0) {                                                     \
        float r = h * dwl;                                                     \
        r += __shfl_xor(r, 32, 64); r += __shfl_xor(r, 16, 64);                \
        r += __shfl_xor(r, 8, 64);  r += __shfl_xor(r, 4, 64);                 \
        r += __shfl_xor(r, 2, 64);  r += __shfl_xor(r, 1, 64);                 \
        if (lane == 0) outb[t] = sigmoidf_(r + db0);                           \
    }                                                                          \
} while (0)

__global__ __launch_bounds__(512, 2)
void lstm_fallback(const float* __restrict__ x, const float* __restrict__ wk,
                   const float* __restrict__ rk, const float* __restrict__ bias,
                   const float* __restrict__ dw, const float* __restrict__ db,
                   float* __restrict__ out) {
    const int b    = blockIdx.x;
    const int tid  = threadIdx.x;
    const int lane = tid & 63;
    const int g    = tid & 255;
    const int kofs = __builtin_amdgcn_readfirstlane((tid >> 8) * 32);
    REP32(DECL_WF) REP32(LOAD_WF) REP32(PIN_WF)
    const float bg  = (kofs == 0) ? bias[g] : 0.0f;
    const float dwl = dw[lane];
    const float db0 = db[0];
    __shared__ float zbuf[2][512];
    float h = 0.0f, c = 0.0f;
    const float* __restrict__ xb   = x + (size_t)b * SS * FF;
    float* __restrict__       outb = out + (size_t)b * SS;
    REP32(DECL_XF)
    { const int offA = __builtin_amdgcn_readfirstlane(kofs); REP32(LOAD_XAF) }
    for (int t = 0; t < SS; t += 2) {
        { const int offB = __builtin_amdgcn_readfirstlane((t + 1) * FF + kofs); REP32(LOAD_XBF) }
        STEPF(t, A);
        { const int t2 = (t + 2 < SS) ? (t + 2) : (SS - 1);
          const int offA = __builtin_amdgcn_readfirstlane(t2 * FF + kofs); REP32(LOAD_XAF) }
        STEPF(t + 1, B);
    }
}

// ================= Host =================
extern "C" void kernel_launch(void* const* d_in, const int* in_sizes, int n_in,
                              void* d_out, int out_size, void* d_ws, size_t ws_size,
                              hipStream_t stream) {
    const float* x    = (const float*)d_in[0];
    const float* wk   = (const float*)d_in[1];
    const float* rk   = (const float*)d_in[2];
    const float* bias = (const float*)d_in[3];
    const float* dw   = (const float*)d_in[4];
    const float* db   = (const float*)d_in[5];
    float* out = (float*)d_out;

    const size_t stateBytes = 2ull * 256 * 64 * sizeof(float);     // 128 KB
    const size_t perStep    = 256ull * NG * sizeof(float);          // 256 KB

    int cs_shift = 0;
    for (int s = 10; s >= 7; --s) {
        if (stateBytes + ((size_t)1 << s) * perStep <= ws_size) { cs_shift = s; break; }
    }
    if (cs_shift == 0) {
        hipLaunchKernelGGL(lstm_fallback, dim3(256), dim3(512), 0, stream,
                           x, wk, rk, bias, dw, db, out);
        return;
    }

    const int CS  = 1 << cs_shift;
    float* state = (float*)d_ws;
    float* xzbuf = (float*)((char*)d_ws + stateBytes);
    const int nch = SS >> cs_shift;

    for (int ci = 0; ci < nch; ++ci) {
        const int t0 = ci << cs_shift;
        hipLaunchKernelGGL(xz_gemm, dim3((256 * CS) / 128), dim3(256), 0, stream,
                           x, wk, bias, xzbuf, t0, cs_shift);
        hipLaunchKernelGGL(lstm_rec, dim3(256), dim3(512), 0, stream,
                           xzbuf, rk, dw, db, out, state, t0, cs_shift, (t0 == 0) ? 1 : 0);
    }
}

// Round 5
// 998.449 us; speedup vs baseline: 1.9565x; 1.9565x over previous
//
#include <hip/hip_runtime.h>

#define SS 1024
#define FF 64
#define NG 256   // 4H gate columns
#define NT 512   // threads per block (8 waves = 2 per SIMD)
#define KH 32    // K-slice per thread (half of F/H)

__device__ __forceinline__ float sigmoidf_(float x) {
    return __builtin_amdgcn_rcpf(1.0f + __expf(-x));
}
__device__ __forceinline__ float tanhf_(float x) {
    return 1.0f - 2.0f * __builtin_amdgcn_rcpf(__expf(2.0f * x) + 1.0f);
}

#define REP32(M) \
  M(0) M(1) M(2) M(3) M(4) M(5) M(6) M(7) \
  M(8) M(9) M(10) M(11) M(12) M(13) M(14) M(15) \
  M(16) M(17) M(18) M(19) M(20) M(21) M(22) M(23) \
  M(24) M(25) M(26) M(27) M(28) M(29) M(30) M(31)

// Weights: the ONLY long-lived per-thread register state (64 floats).
#define DECL_W(i)  float wx##i, wh##i;
#define LOAD_W(i)  wx##i = wk[(kofs + (i)) * NG + g]; wh##i = rk[(kofs + (i)) * NG + g];
#define PIN_W(i)   asm volatile("" : "+v"(wx##i), "+v"(wh##i));

// h broadcast: h[l] lives in lane l of EVERY wave (replicated) -> v_readlane
// (dst is an SGPR; the FMA consumes it as its one scalar operand).
#define FH4(i0,i1,i2,i3) \
  a0 += __int_as_float(__builtin_amdgcn_readlane(hb, kofs + i0)) * wh##i0; \
  a1 += __int_as_float(__builtin_amdgcn_readlane(hb, kofs + i1)) * wh##i1; \
  a2 += __int_as_float(__builtin_amdgcn_readlane(hb, kofs + i2)) * wh##i2; \
  a3 += __int_as_float(__builtin_amdgcn_readlane(hb, kofs + i3)) * wh##i3;
#define FH_ALL FH4(0,1,2,3) FH4(4,5,6,7) FH4(8,9,10,11) FH4(12,13,14,15) \
               FH4(16,17,18,19) FH4(20,21,22,23) FH4(24,25,26,27) FH4(28,29,30,31)

// x broadcast: x_t[l] lives in lane l (per-lane coalesced load, 4-slot
// rotation) -> same readlane pattern. NO SGPR staging (round 2/3's
// SGPR_Count=112 exhaustion is what triggered the wholesale scratch demotion).
#define FX4(S,i0,i1,i2,i3) \
  a0 += __int_as_float(__builtin_amdgcn_readlane(x##S, kofs + i0)) * wx##i0; \
  a1 += __int_as_float(__builtin_amdgcn_readlane(x##S, kofs + i1)) * wx##i1; \
  a2 += __int_as_float(__builtin_amdgcn_readlane(x##S, kofs + i2)) * wx##i2; \
  a3 += __int_as_float(__builtin_amdgcn_readlane(x##S, kofs + i3)) * wx##i3;
#define FX_ALL(S) FX4(S,0,1,2,3) FX4(S,4,5,6,7) FX4(S,8,9,10,11) FX4(S,12,13,14,15) \
                  FX4(S,16,17,18,19) FX4(S,20,21,22,23) FX4(S,24,25,26,27) FX4(S,28,29,30,31)

// lgkmcnt-only barrier: does NOT drain vmcnt, so the 4-step-ahead x loads
// stay in flight across step boundaries.
#define RAW_BARRIER() asm volatile("s_waitcnt lgkmcnt(0)\n\ts_barrier" ::: "memory")

#define STEP(T, S) do {                                                        \
    const int bsel = (T) & 1;                                                  \
    float a0 = bg, a1 = 0.0f, a2 = 0.0f, a3 = 0.0f;                            \
    const int hb = __float_as_int(h);                                          \
    FH_ALL                                                                     \
    FX_ALL(S)                                                                  \
    {   /* refill this slot for step T+4 (in flight ~3 full steps) */          \
        const int tt = ((T) + 4 < SS) ? ((T) + 4) : (SS - 1);                  \
        x##S = xbi[tt * FF + lane];                                            \
    }                                                                          \
    zbuf[bsel][tid] = (a0 + a1) + (a2 + a3);                                   \
    RAW_BARRIER();                                                             \
    const float zi = zbuf[bsel][lane]       + zbuf[bsel][256 + lane];          \
    const float zf = zbuf[bsel][64 + lane]  + zbuf[bsel][320 + lane];          \
    const float zc = zbuf[bsel][128 + lane] + zbuf[bsel][384 + lane];          \
    const float zo = zbuf[bsel][192 + lane] + zbuf[bsel][448 + lane];          \
    const float ig = sigmoidf_(zi);                                            \
    const float fg = sigmoidf_(zf);                                            \
    const float og = sigmoidf_(zo);                                            \
    c = fg * c + ig * tanhf_(zc);                                              \
    h = og * tanhf_(c);                                                        \
    if ((tid >> 6) == 0) {                                                     \
        float r = h * dwl;                                                     \
        r += __shfl_xor(r, 32, 64); r += __shfl_xor(r, 16, 64);                \
        r += __shfl_xor(r, 8, 64);  r += __shfl_xor(r, 4, 64);                 \
        r += __shfl_xor(r, 2, 64);  r += __shfl_xor(r, 1, 64);                 \
        if (lane == 0) outb[T] = sigmoidf_(r + db0);                           \
    }                                                                          \
} while (0)

// One block per batch element (256 blocks = 1/CU, 8 waves = 2/SIMD).
// Thread (g = tid&255, half = tid>>8) computes the k in [half*32,(half+1)*32)
// partial of gate column g. 64 weight floats are the only long-lived VGPR
// state (~90 VGPR total demand, cap 256 at 2 waves/SIMD). h and c carried
// per-lane (col = lane), replicated per wave.
__global__ __launch_bounds__(NT, 2)
void lstm_fused(const float* __restrict__ x,
                const float* __restrict__ wk,
                const float* __restrict__ rk,
                const float* __restrict__ bias,
                const float* __restrict__ dw,
                const float* __restrict__ db,
                float* __restrict__ out) {
    const int b    = blockIdx.x;
    const int tid  = threadIdx.x;
    const int lane = tid & 63;
    const int g    = tid & 255;                                        // gate column
    const int kofs = __builtin_amdgcn_readfirstlane((tid >> 8) * KH);  // 0 or 32

    REP32(DECL_W)
    REP32(LOAD_W)
    REP32(PIN_W)

    const float bg  = (kofs == 0) ? bias[g] : 0.0f;   // bias counted once
    const float dwl = dw[lane];
    const float db0 = db[0];

    __shared__ float zbuf[2][NT];

    float h = 0.0f, c = 0.0f;
    const int* __restrict__ xbi  = (const int*)(x + (size_t)b * SS * FF);
    float* __restrict__     outb = out + (size_t)b * SS;

    // 4-slot rotating x prefetch: lane l holds x_t[l] (one VGPR per slot).
    int xA = xbi[0 * FF + lane];
    int xB = xbi[1 * FF + lane];
    int xC = xbi[2 * FF + lane];
    int xD = xbi[3 * FF + lane];

    for (int t = 0; t < SS; t += 4) {
        STEP(t + 0, A);
        STEP(t + 1, B);
        STEP(t + 2, C);
        STEP(t + 3, D);
    }
}

extern "C" void kernel_launch(void* const* d_in, const int* in_sizes, int n_in,
                              void* d_out, int out_size, void* d_ws, size_t ws_size,
                              hipStream_t stream) {
    const float* x    = (const float*)d_in[0];
    const float* wk   = (const float*)d_in[1];
    const float* rk   = (const float*)d_in[2];
    const float* bias = (const float*)d_in[3];
    const float* dw   = (const float*)d_in[4];
    const float* db   = (const float*)d_in[5];
    float* out = (float*)d_out;

    hipLaunchKernelGGL(lstm_fused, dim3(256), dim3(NT), 0, stream,
                       x, wk, rk, bias, dw, db, out);
}